// Round 1
// baseline (816.311 us; speedup 1.0000x reference)
//
#include <hip/hip_runtime.h>

#define NPTS 4096
#define CDIM 256
#define C4DIM 64

// ---------------------------------------------------------------------------
// Projection kernel: q = Wq x + bq, k = Wk x + bk, v = Wv x + bv
// grid (NPTS/128, 6, B), block 256.  blockIdx.y: 0->q, 1->k, 2..5->v rows
// Each block computes a 64(out-ch) x 128(n) tile, K = 256 in chunks of 64.
// ---------------------------------------------------------------------------
__global__ __launch_bounds__(256) void proj_kernel(
    const float* __restrict__ x,
    const float* __restrict__ Wq, const float* __restrict__ bq,
    const float* __restrict__ Wk, const float* __restrict__ bk,
    const float* __restrict__ Wv, const float* __restrict__ bv,
    float* __restrict__ qo, float* __restrict__ ko, float* __restrict__ vo)
{
    const int nb = blockIdx.x;
    const int ot = blockIdx.y;
    const int b  = blockIdx.z;
    const int t  = threadIdx.x;

    const float* W; const float* bias; float* outp; int obase;
    if (ot == 0)      { W = Wq; bias = bq; outp = qo + (size_t)b*C4DIM*NPTS; obase = 0; }
    else if (ot == 1) { W = Wk; bias = bk; outp = ko + (size_t)b*C4DIM*NPTS; obase = 0; }
    else              { W = Wv; bias = bv; outp = vo + (size_t)b*CDIM*NPTS;  obase = (ot-2)*64; }

    __shared__ float Xs[64][128];   // [c_chunk][n]
    __shared__ float Wt[64][68];    // [c_chunk][o]  (transposed), pad 68

    const int og = t >> 5;          // 0..7  -> o = og*8 + {0..7}
    const int ng = t & 31;          // 0..31 -> n = n0 + ng*4 + {0..3}
    const int n0 = nb * 128;
    const float* xb = x + (size_t)b*CDIM*NPTS;

    float acc[8][4];
    #pragma unroll
    for (int i=0;i<8;i++)
        #pragma unroll
        for (int j=0;j<4;j++) acc[i][j]=0.f;

    for (int c0 = 0; c0 < CDIM; c0 += 64) {
        // stage X tile: 64 x 128 floats
        #pragma unroll
        for (int i=0;i<8;i++) {
            int lin = t + 256*i;           // 0..2047 (float4 units)
            int row = lin >> 5, col4 = lin & 31;
            float4 v4 = *(const float4*)&xb[(size_t)(c0+row)*NPTS + n0 + col4*4];
            *(float4*)&Xs[row][col4*4] = v4;
        }
        // stage W tile transposed: Wt[cc][o]
        #pragma unroll
        for (int i=0;i<4;i++) {
            int lin = t + 256*i;           // 0..1023
            int orow = lin >> 4, c4 = lin & 15;
            float4 v4 = *(const float4*)&W[(size_t)(obase+orow)*CDIM + c0 + c4*4];
            Wt[c4*4+0][orow] = v4.x;
            Wt[c4*4+1][orow] = v4.y;
            Wt[c4*4+2][orow] = v4.z;
            Wt[c4*4+3][orow] = v4.w;
        }
        __syncthreads();
        #pragma unroll 8
        for (int cc=0; cc<64; cc++) {
            float4 w0 = *(const float4*)&Wt[cc][og*8];
            float4 w1 = *(const float4*)&Wt[cc][og*8+4];
            float4 xv = *(const float4*)&Xs[cc][ng*4];
            float wv[8] = {w0.x,w0.y,w0.z,w0.w,w1.x,w1.y,w1.z,w1.w};
            float xa[4] = {xv.x,xv.y,xv.z,xv.w};
            #pragma unroll
            for (int oi=0;oi<8;oi++)
                #pragma unroll
                for (int ni=0;ni<4;ni++)
                    acc[oi][ni] += wv[oi]*xa[ni];
        }
        __syncthreads();
    }
    #pragma unroll
    for (int oi=0;oi<8;oi++) {
        int o = og*8 + oi;
        float bsv = bias[obase + o];
        float4 r;
        r.x = acc[oi][0]+bsv; r.y = acc[oi][1]+bsv;
        r.z = acc[oi][2]+bsv; r.w = acc[oi][3]+bsv;
        *(float4*)&outp[(size_t)(obase+o)*NPTS + n0 + ng*4] = r;
    }
}

// ---------------------------------------------------------------------------
// Flash attention: grid (NPTS/64, B), block 512.
// Block handles 64 query rows (i0..i0+63), all 256 channels, iterating over
// 64-wide j tiles with online softmax.
// QK mapping:  jg=t&15 (4 j each), rg=t>>4 (2 rows each) -> 8 scores/thread
// PV mapping:  chg=t&31 (ch = chg+32*ci, 8 ch), rowg=t>>5 (4 rows) -> 32 acc
// ---------------------------------------------------------------------------
__global__ __launch_bounds__(512, 1) void attn_kernel(
    const float* __restrict__ qin, const float* __restrict__ kin,
    const float* __restrict__ vin, const float* __restrict__ xin,
    const float* __restrict__ gptr, float* __restrict__ out)
{
    __shared__ float Qs[64][68];     // [d][r]
    __shared__ float Ks[64][68];     // [d][j]
    __shared__ float Ps[64][68];     // [r][j]
    __shared__ float Vs[256][68];    // [c][j]; reused as O[c][r] in epilogue
    __shared__ float alpha_s[64];
    __shared__ float l_s[64];

    const int t  = threadIdx.x;
    const int b  = blockIdx.y;
    const int i0 = blockIdx.x * 64;

    const float* qb = qin + (size_t)b*C4DIM*NPTS;
    const float* kb = kin + (size_t)b*C4DIM*NPTS;
    const float* vb = vin + (size_t)b*CDIM*NPTS;

    // stage Q once: Qs[d][r] = q[b][d][i0+r]
    #pragma unroll
    for (int i=0;i<2;i++){
        int lin = t + 512*i;           // 0..1023
        int d = lin >> 4, r4 = lin & 15;
        float4 v4 = *(const float4*)&qb[(size_t)d*NPTS + i0 + r4*4];
        *(float4*)&Qs[d][r4*4] = v4;
    }

    const int jg   = t & 15;
    const int rg   = t >> 4;    // 0..31
    const int chg  = t & 31;
    const int rowg = t >> 5;    // 0..15

    float m_r[2] = {-1e30f, -1e30f};
    float l_r[2] = {0.f, 0.f};
    float oacc[4][8];
    #pragma unroll
    for (int a=0;a<4;a++)
        #pragma unroll
        for (int c=0;c<8;c++) oacc[a][c]=0.f;

    for (int j0 = 0; j0 < NPTS; j0 += 64) {
        __syncthreads();   // previous tile fully consumed
        // stage K tile: Ks[d][j]
        #pragma unroll
        for (int i=0;i<2;i++){
            int lin = t + 512*i;
            int d = lin >> 4, j4 = lin & 15;
            float4 v4 = *(const float4*)&kb[(size_t)d*NPTS + j0 + j4*4];
            *(float4*)&Ks[d][j4*4] = v4;
        }
        // stage V tile: Vs[c][j]
        #pragma unroll
        for (int i=0;i<8;i++){
            int lin = t + 512*i;           // 0..4095
            int c = lin >> 4, j4 = lin & 15;
            float4 v4 = *(const float4*)&vb[(size_t)c*NPTS + j0 + j4*4];
            *(float4*)&Vs[c][j4*4] = v4;
        }
        __syncthreads();

        // ---- QK: s[r][j], r = rg*2+ri, j = jg*4+jj
        float s[2][4];
        #pragma unroll
        for (int a=0;a<2;a++)
            #pragma unroll
            for (int c=0;c<4;c++) s[a][c]=0.f;
        #pragma unroll 8
        for (int d=0; d<64; d++){
            float2 qv = *(const float2*)&Qs[d][rg*2];
            float4 kv = *(const float4*)&Ks[d][jg*4];
            s[0][0] += qv.x*kv.x; s[0][1] += qv.x*kv.y;
            s[0][2] += qv.x*kv.z; s[0][3] += qv.x*kv.w;
            s[1][0] += qv.y*kv.x; s[1][1] += qv.y*kv.y;
            s[1][2] += qv.y*kv.z; s[1][3] += qv.y*kv.w;
        }

        // ---- online softmax over this tile (rows shared by 16 jg lanes)
        #pragma unroll
        for (int ri=0; ri<2; ri++){
            float tm = fmaxf(fmaxf(s[ri][0],s[ri][1]), fmaxf(s[ri][2],s[ri][3]));
            #pragma unroll
            for (int off=1; off<16; off<<=1)
                tm = fmaxf(tm, __shfl_xor(tm, off));
            float mnew = fmaxf(m_r[ri], tm);
            float4 p;
            p.x = __expf(s[ri][0]-mnew);
            p.y = __expf(s[ri][1]-mnew);
            p.z = __expf(s[ri][2]-mnew);
            p.w = __expf(s[ri][3]-mnew);
            float ps = p.x+p.y+p.z+p.w;
            #pragma unroll
            for (int off=1; off<16; off<<=1)
                ps += __shfl_xor(ps, off);
            float al = __expf(m_r[ri]-mnew);
            l_r[ri] = l_r[ri]*al + ps;
            m_r[ri] = mnew;
            *(float4*)&Ps[rg*2+ri][jg*4] = p;
            if (jg == 0) alpha_s[rg*2+ri] = al;
        }
        __syncthreads();

        // ---- PV: oacc[ri][ci] = alpha*oacc + sum_j P[row][j]*V[ch][j]
        float al[4];
        #pragma unroll
        for (int ri=0; ri<4; ri++) al[ri] = alpha_s[rowg*4+ri];
        #pragma unroll
        for (int ri=0; ri<4; ri++)
            #pragma unroll
            for (int ci=0; ci<8; ci++) oacc[ri][ci] *= al[ri];

        #pragma unroll 2
        for (int j4=0; j4<16; j4++){
            float4 pv[4], vv[8];
            #pragma unroll
            for (int ri=0; ri<4; ri++) pv[ri] = *(const float4*)&Ps[rowg*4+ri][j4*4];
            #pragma unroll
            for (int ci=0; ci<8; ci++) vv[ci] = *(const float4*)&Vs[chg+32*ci][j4*4];
            #pragma unroll
            for (int ri=0; ri<4; ri++)
                #pragma unroll
                for (int ci=0; ci<8; ci++)
                    oacc[ri][ci] += pv[ri].x*vv[ci].x + pv[ri].y*vv[ci].y
                                  + pv[ri].z*vv[ci].z + pv[ri].w*vv[ci].w;
        }
    }

    // ---- epilogue: normalize, scale by gamma, transpose through LDS, +x
    if (jg == 0) {
        l_s[rg*2+0] = l_r[0];
        l_s[rg*2+1] = l_r[1];
    }
    __syncthreads();   // l_s visible; everyone done reading Vs/Ps

    const float g = gptr[0];
    float linv[4];
    #pragma unroll
    for (int ri=0; ri<4; ri++) linv[ri] = 1.0f / l_s[rowg*4+ri];
    #pragma unroll
    for (int ci=0; ci<8; ci++){
        int c = chg + 32*ci;
        #pragma unroll
        for (int ri=0; ri<4; ri++)
            Vs[c][rowg*4+ri] = g * oacc[ri][ci] * linv[ri];   // O[c][r]
    }
    __syncthreads();

    const float* xb = xin + (size_t)b*CDIM*NPTS;
    float*       ob = out + (size_t)b*CDIM*NPTS;
    #pragma unroll
    for (int i=0;i<8;i++){
        int lin = t + 512*i;           // 0..4095
        int c = lin >> 4, r4 = lin & 15;
        size_t base = (size_t)c*NPTS + i0 + r4*4;
        float4 ov = *(const float4*)&Vs[c][r4*4];
        float4 xv = *(const float4*)&xb[base];
        float4 r;
        r.x = ov.x + xv.x; r.y = ov.y + xv.y;
        r.z = ov.z + xv.z; r.w = ov.w + xv.w;
        *(float4*)&ob[base] = r;
    }
}

extern "C" void kernel_launch(void* const* d_in, const int* in_sizes, int n_in,
                              void* d_out, int out_size, void* d_ws, size_t ws_size,
                              hipStream_t stream) {
    const float* x     = (const float*)d_in[0];
    const float* Wq    = (const float*)d_in[1];
    const float* bq    = (const float*)d_in[2];
    const float* Wk    = (const float*)d_in[3];
    const float* bk    = (const float*)d_in[4];
    const float* Wv    = (const float*)d_in[5];
    const float* bv    = (const float*)d_in[6];
    const float* gamma = (const float*)d_in[7];

    const int B = 4;
    float* q_ws = (float*)d_ws;                       //  4 MB
    float* k_ws = q_ws + (size_t)B*C4DIM*NPTS;        //  4 MB
    float* v_ws = k_ws + (size_t)B*C4DIM*NPTS;        // 16 MB  (total 24 MB)

    proj_kernel<<<dim3(NPTS/128, 6, B), 256, 0, stream>>>(
        x, Wq, bq, Wk, bk, Wv, bv, q_ws, k_ws, v_ws);

    attn_kernel<<<dim3(NPTS/64, B), 512, 0, stream>>>(
        q_ws, k_ws, v_ws, x, gamma, (float*)d_out);
}

// Round 2
// 289.802 us; speedup vs baseline: 2.8168x; 2.8168x over previous
//
#include <hip/hip_runtime.h>

#define NPTS 4096
#define CDIM 256
#define C4DIM 64

typedef __bf16 bf16x8 __attribute__((ext_vector_type(8)));
typedef float  f32x4  __attribute__((ext_vector_type(4)));

// ---------------------------------------------------------------------------
// Projection kernel (fp32 VALU GEMM, bf16 outputs):
//   qT[b][n][64] = (Wq x + bq)^T   (bf16, n-major for MFMA A-frag staging)
//   kT[b][n][64] = (Wk x + bk)^T   (bf16)
//   v [b][c][n]  =  Wv x + bv      (bf16, c-major for MFMA B-frag staging)
// grid (NPTS/128, 6, B), block 256.  blockIdx.y: 0->q, 1->k, 2..5->v rows
// ---------------------------------------------------------------------------
__global__ __launch_bounds__(256) void proj_kernel(
    const float* __restrict__ x,
    const float* __restrict__ Wq, const float* __restrict__ bq,
    const float* __restrict__ Wk, const float* __restrict__ bk,
    const float* __restrict__ Wv, const float* __restrict__ bv,
    __bf16* __restrict__ qT, __bf16* __restrict__ kT, __bf16* __restrict__ vo)
{
    const int nb = blockIdx.x;
    const int ot = blockIdx.y;
    const int b  = blockIdx.z;
    const int t  = threadIdx.x;

    const float* W; const float* bias; int obase;
    if (ot == 0)      { W = Wq; bias = bq; obase = 0; }
    else if (ot == 1) { W = Wk; bias = bk; obase = 0; }
    else              { W = Wv; bias = bv; obase = (ot-2)*64; }

    __shared__ float Xs[64][128];   // [c_chunk][n]
    __shared__ float Wt[64][68];    // [c_chunk][o]  (transposed), pad 68

    const int og = t >> 5;          // 0..7  -> o = og*8 + {0..7}
    const int ng = t & 31;          // 0..31 -> n = n0 + ng*4 + {0..3}
    const int n0 = nb * 128;
    const float* xb = x + (size_t)b*CDIM*NPTS;

    float acc[8][4];
    #pragma unroll
    for (int i=0;i<8;i++)
        #pragma unroll
        for (int j=0;j<4;j++) acc[i][j]=0.f;

    for (int c0 = 0; c0 < CDIM; c0 += 64) {
        #pragma unroll
        for (int i=0;i<8;i++) {
            int lin = t + 256*i;
            int row = lin >> 5, col4 = lin & 31;
            float4 v4 = *(const float4*)&xb[(size_t)(c0+row)*NPTS + n0 + col4*4];
            *(float4*)&Xs[row][col4*4] = v4;
        }
        #pragma unroll
        for (int i=0;i<4;i++) {
            int lin = t + 256*i;
            int orow = lin >> 4, c4 = lin & 15;
            float4 v4 = *(const float4*)&W[(size_t)(obase+orow)*CDIM + c0 + c4*4];
            Wt[c4*4+0][orow] = v4.x;
            Wt[c4*4+1][orow] = v4.y;
            Wt[c4*4+2][orow] = v4.z;
            Wt[c4*4+3][orow] = v4.w;
        }
        __syncthreads();
        #pragma unroll 8
        for (int cc=0; cc<64; cc++) {
            float4 w0 = *(const float4*)&Wt[cc][og*8];
            float4 w1 = *(const float4*)&Wt[cc][og*8+4];
            float4 xv = *(const float4*)&Xs[cc][ng*4];
            float wv[8] = {w0.x,w0.y,w0.z,w0.w,w1.x,w1.y,w1.z,w1.w};
            float xa[4] = {xv.x,xv.y,xv.z,xv.w};
            #pragma unroll
            for (int oi=0;oi<8;oi++)
                #pragma unroll
                for (int ni=0;ni<4;ni++)
                    acc[oi][ni] += wv[oi]*xa[ni];
        }
        __syncthreads();
    }

    if (ot < 2) {
        // write transposed bf16: qT[(b*N + n)*64 + o], 8 contiguous o per store
        __bf16* outp = (ot == 0 ? qT : kT) + (size_t)b*NPTS*C4DIM;
        float bsv[8];
        #pragma unroll
        for (int oi=0;oi<8;oi++) bsv[oi] = bias[og*8+oi];
        #pragma unroll
        for (int ni=0;ni<4;ni++) {
            int n = n0 + ng*4 + ni;
            union { __bf16 h[8]; uint4 u; } pk;
            #pragma unroll
            for (int oi=0;oi<8;oi++) pk.h[oi] = (__bf16)(acc[oi][ni] + bsv[oi]);
            *(uint4*)&outp[(size_t)n*C4DIM + og*8] = pk.u;
        }
    } else {
        __bf16* outp = vo + (size_t)b*CDIM*NPTS;
        #pragma unroll
        for (int oi=0;oi<8;oi++) {
            int o = og*8 + oi;
            float bsv = bias[obase + o];
            union { __bf16 h[4]; uint2 u; } pk;
            #pragma unroll
            for (int ni=0;ni<4;ni++) pk.h[ni] = (__bf16)(acc[oi][ni] + bsv);
            *(uint2*)&outp[(size_t)(obase+o)*NPTS + n0 + ng*4] = pk.u;
        }
    }
}

// ---------------------------------------------------------------------------
// MFMA flash attention.
// grid (NPTS/128, CDIM/128, B), block 256 (4 waves).
// Block: 128 q-rows (i0..) x 128 channels (c0..), j-tiles of 64, online
// softmax. QK redundantly computed by both c-slices (cheap vs staging win).
// Per wave: i-strip of 32 rows. 16x16x32 bf16 MFMA.
//   A/B frag: [m|n = lane&15][k = quad*8 + jj]; C/D: col=lane&15, row=quad*4+reg
// ---------------------------------------------------------------------------
__global__ __launch_bounds__(256, 2) void attn_kernel(
    const __bf16* __restrict__ qT, const __bf16* __restrict__ kT,
    const __bf16* __restrict__ vin, const float* __restrict__ xin,
    const float* __restrict__ gptr, float* __restrict__ out)
{
    __shared__ __align__(16) unsigned char smem_raw[64512];
    auto Qs = (__bf16 (*)[72])(smem_raw);            // [128][72]  18432 B
    auto Ks = (__bf16 (*)[72])(smem_raw + 18432);    // [64][72]    9216 B
    auto Ps = (__bf16 (*)[72])(smem_raw + 27648);    // [128][72]  18432 B
    auto Vs = (__bf16 (*)[72])(smem_raw + 46080);    // [128][72]  18432 B
    auto OT = (float  (*)[68])(smem_raw);            // [128][68]  34816 B (epilogue)

    const int t    = threadIdx.x;
    const int w    = t >> 6;
    const int lane = t & 63;
    const int quad = lane >> 4;
    const int l16  = lane & 15;

    const int b  = blockIdx.z;
    const int i0 = blockIdx.x * 128;
    const int c0 = blockIdx.y * 128;

    const __bf16* qb = qT  + (size_t)b*NPTS*C4DIM;
    const __bf16* kb = kT  + (size_t)b*NPTS*C4DIM;
    const __bf16* vb = vin + (size_t)b*CDIM*NPTS;

    // stage Q once: Qs[i][d]
    #pragma unroll
    for (int s=0;s<4;s++){
        int lin = t + 256*s;            // 0..1023
        int row = lin >> 3, col = (lin & 7) * 8;
        *(uint4*)&Qs[row][col] = *(const uint4*)&qb[(size_t)(i0+row)*C4DIM + col];
    }

    f32x4 O[2][8];
    #pragma unroll
    for (int tr=0;tr<2;tr++)
        #pragma unroll
        for (int tc=0;tc<8;tc++) O[tr][tc] = (f32x4)(0.f);

    float m_[2][4], l_[2][4], al_[2][4];
    #pragma unroll
    for (int tr=0;tr<2;tr++)
        #pragma unroll
        for (int r=0;r<4;r++){ m_[tr][r] = -1e30f; l_[tr][r] = 0.f; }

    for (int j0 = 0; j0 < NPTS; j0 += 64) {
        __syncthreads();   // previous iter fully consumed
        // stage K tile: Ks[j][d]
        #pragma unroll
        for (int s=0;s<2;s++){
            int lin = t + 256*s;        // 0..511
            int row = lin >> 3, col = (lin & 7) * 8;
            *(uint4*)&Ks[row][col] = *(const uint4*)&kb[(size_t)(j0+row)*C4DIM + col];
        }
        // stage V tile: Vs[c][j]
        #pragma unroll
        for (int s=0;s<4;s++){
            int lin = t + 256*s;        // 0..1023
            int row = lin >> 3, col = (lin & 7) * 8;
            *(uint4*)&Vs[row][col] = *(const uint4*)&vb[(size_t)(c0+row)*NPTS + j0 + col];
        }
        __syncthreads();

        // ---- QK: S[tr][tc] = Q-strip x K-tile
        f32x4 S[2][4];
        #pragma unroll
        for (int tr=0;tr<2;tr++)
            #pragma unroll
            for (int tc=0;tc<4;tc++) S[tr][tc] = (f32x4)(0.f);

        #pragma unroll
        for (int kc=0; kc<2; kc++){
            bf16x8 aq[2], bk[4];
            #pragma unroll
            for (int tr=0;tr<2;tr++)
                aq[tr] = *(const bf16x8*)&Qs[32*w + 16*tr + l16][kc*32 + quad*8];
            #pragma unroll
            for (int tc=0;tc<4;tc++)
                bk[tc] = *(const bf16x8*)&Ks[16*tc + l16][kc*32 + quad*8];
            #pragma unroll
            for (int tr=0;tr<2;tr++)
                #pragma unroll
                for (int tc=0;tc<4;tc++)
                    S[tr][tc] = __builtin_amdgcn_mfma_f32_16x16x32_bf16(
                        aq[tr], bk[tc], S[tr][tc], 0, 0, 0);
        }

        // ---- online softmax; each lane owns rows (tr, reg) = 32w+16tr+4quad+reg
        #pragma unroll
        for (int tr=0;tr<2;tr++){
            #pragma unroll
            for (int r=0;r<4;r++){
                float mx = fmaxf(fmaxf(S[0+tr][0][r], S[tr][1][r]),
                                 fmaxf(S[tr][2][r], S[tr][3][r]));
                #pragma unroll
                for (int off=1; off<16; off<<=1)
                    mx = fmaxf(mx, __shfl_xor(mx, off));
                float mnew = fmaxf(m_[tr][r], mx);
                float p0 = __expf(S[tr][0][r] - mnew);
                float p1 = __expf(S[tr][1][r] - mnew);
                float p2 = __expf(S[tr][2][r] - mnew);
                float p3 = __expf(S[tr][3][r] - mnew);
                float ps = p0+p1+p2+p3;
                #pragma unroll
                for (int off=1; off<16; off<<=1)
                    ps += __shfl_xor(ps, off);
                float alpha = __expf(m_[tr][r] - mnew);
                l_[tr][r] = l_[tr][r]*alpha + ps;
                m_[tr][r] = mnew;
                al_[tr][r] = alpha;
                int row = 32*w + 16*tr + 4*quad + r;
                Ps[row][      l16] = (__bf16)p0;
                Ps[row][16 + l16] = (__bf16)p1;
                Ps[row][32 + l16] = (__bf16)p2;
                Ps[row][48 + l16] = (__bf16)p3;
            }
        }

        // ---- rescale O by alpha (rows match C-layout regs)
        #pragma unroll
        for (int tr=0;tr<2;tr++)
            #pragma unroll
            for (int tc=0;tc<8;tc++)
                #pragma unroll
                for (int r=0;r<4;r++) O[tr][tc][r] *= al_[tr][r];

        // ---- PV: O[tr][tcc] += P-strip x V-tile  (same-wave LDS dep: no barrier)
        #pragma unroll
        for (int jc=0; jc<2; jc++){
            bf16x8 ap[2], bv[8];
            #pragma unroll
            for (int tr=0;tr<2;tr++)
                ap[tr] = *(const bf16x8*)&Ps[32*w + 16*tr + l16][jc*32 + quad*8];
            #pragma unroll
            for (int tc=0;tc<8;tc++)
                bv[tc] = *(const bf16x8*)&Vs[16*tc + l16][jc*32 + quad*8];
            #pragma unroll
            for (int tr=0;tr<2;tr++)
                #pragma unroll
                for (int tc=0;tc<8;tc++)
                    O[tr][tc] = __builtin_amdgcn_mfma_f32_16x16x32_bf16(
                        ap[tr], bv[tc], O[tr][tc], 0, 0, 0);
        }
    }

    // ---- epilogue: gamma*O/l, transpose via LDS, +x, coalesced store
    __syncthreads();   // all PV reads done; OT overlays Qs/Ks/Ps
    const float g = gptr[0];
    float inv_l[2][4];
    #pragma unroll
    for (int tr=0;tr<2;tr++)
        #pragma unroll
        for (int r=0;r<4;r++) inv_l[tr][r] = 1.0f / l_[tr][r];

    const float* xb  = xin + (size_t)b*CDIM*NPTS;
    float*       ob  = out + (size_t)b*CDIM*NPTS;

    #pragma unroll
    for (int tr=0;tr<2;tr++){
        if (tr) __syncthreads();   // previous round's OT reads done
        #pragma unroll
        for (int tc=0;tc<8;tc++){
            int c = 16*tc + l16;
            float4 f;
            f.x = g * O[tr][tc][0] * inv_l[tr][0];
            f.y = g * O[tr][tc][1] * inv_l[tr][1];
            f.z = g * O[tr][tc][2] * inv_l[tr][2];
            f.w = g * O[tr][tc][3] * inv_l[tr][3];
            *(float4*)&OT[c][16*w + 4*quad] = f;
        }
        __syncthreads();
        #pragma unroll
        for (int s=0;s<8;s++){
            int lin = t + 256*s;          // 0..2047
            int c = lin >> 4, col = (lin & 15) * 4;
            int il = (col >> 4)*32 + 16*tr + (col & 15);
            size_t gi = (size_t)(c0 + c)*NPTS + i0 + il;
            float4 ov = *(const float4*)&OT[c][col];
            float4 xv = *(const float4*)&xb[gi];
            float4 rr;
            rr.x = ov.x + xv.x; rr.y = ov.y + xv.y;
            rr.z = ov.z + xv.z; rr.w = ov.w + xv.w;
            *(float4*)&ob[gi] = rr;
        }
    }
}

extern "C" void kernel_launch(void* const* d_in, const int* in_sizes, int n_in,
                              void* d_out, int out_size, void* d_ws, size_t ws_size,
                              hipStream_t stream) {
    const float* x     = (const float*)d_in[0];
    const float* Wq    = (const float*)d_in[1];
    const float* bq    = (const float*)d_in[2];
    const float* Wk    = (const float*)d_in[3];
    const float* bk    = (const float*)d_in[4];
    const float* Wv    = (const float*)d_in[5];
    const float* bv    = (const float*)d_in[6];
    const float* gamma = (const float*)d_in[7];

    const int B = 4;
    __bf16* qT = (__bf16*)d_ws;                         // 4*4096*64  = 2 MB
    __bf16* kT = qT + (size_t)B*NPTS*C4DIM;             // 2 MB
    __bf16* v  = kT + (size_t)B*NPTS*C4DIM;             // 4*256*4096 = 8 MB

    proj_kernel<<<dim3(NPTS/128, 6, B), 256, 0, stream>>>(
        x, Wq, bq, Wk, bk, Wv, bv, qT, kT, v);

    attn_kernel<<<dim3(NPTS/128, CDIM/128, B), 256, 0, stream>>>(
        qT, kT, v, x, gamma, (float*)d_out);
}